// Round 4
// baseline (113.726 us; speedup 1.0000x reference)
//
#include <hip/hip_runtime.h>
#include <hip/hip_cooperative_groups.h>
#include <stdint.h>

namespace cg = cooperative_groups;

// ---- problem constants ----
#define NPIX   4194304      // 8*512*1024
#define NGRP   (NPIX / 4)   // float4 groups
#define KSEL   1258291      // int(NPIX * 0.3)
#define HWSZ   524288       // 512*1024 (class-plane stride in elements)
#define NCLS   20

// coop config
#define CBLOCKS 512
#define CITERS  8           // float4 groups per thread (32 pixels/thread)

// fallback config (round-2 proven)
#define CE_BLOCKS 1024
#define CE_ITERS  4
#define H_BLOCKS  512
#define H_THREADS 512
#define H_ITERS   4

// ---- workspace layout (bytes) ----
#define OFF_PSUM 0          // double[1024] per-block CE partial sums
#define OFF_BIGP 8192       // double[512] coop big-sums | fallback b1p[512]
#define OFF_B2P  12288      // double[512] fallback b2p
#define OFF_H1   16384      // uint[2048]
#define OFF_H2   24576      // uint[2048]
#define OFF_H3   32768      // uint[1024]
#define OFF_S3   36864      // double[1024] level-3 per-bin value sums
#define OFF_SEL  45056      // uint[16] (fallback)
#define OFF_CE   65536      // float[NPIX] (fallback)
#define MEMSET_LEN (OFF_SEL + 64 - OFF_H1)

__device__ __forceinline__ double block_reduce_d(double d, double* lred, int nwaves) {
    __syncthreads();  // protect lred reuse across calls
    for (int off = 32; off > 0; off >>= 1) d += __shfl_down(d, off);
    int wid  = threadIdx.x >> 6;
    int lane = threadIdx.x & 63;
    if (lane == 0) lred[wid] = d;
    __syncthreads();
    double r = 0.0;
    if (threadIdx.x == 0) {
        for (int i = 0; i < nwaves; ++i) r += lred[i];
    }
    return r;  // valid on thread 0 only
}

// find bin where descending suffix-count crosses ktar; writes *sbin,*skrem (one thread)
__device__ __forceinline__ void suffix_select(const unsigned* h, unsigned* tmp,
                                              int chunk, unsigned ktar,
                                              unsigned* sbin, unsigned* skrem) {
    int t = threadIdx.x;
    unsigned lsum = 0;
    for (int j = 0; j < chunk; ++j) lsum += h[t * chunk + j];
    tmp[t] = lsum;
    __syncthreads();
    for (int off = 1; off < 256; off <<= 1) {
        unsigned add = (t + off < 256) ? tmp[t + off] : 0u;
        __syncthreads();
        tmp[t] += add;
        __syncthreads();
    }
    unsigned cum = tmp[t] - lsum;   // count in bins strictly above my chunk
    for (int j = chunk - 1; j >= 0; --j) {
        unsigned hv = h[t * chunk + j];
        if (cum < ktar && cum + hv >= ktar) { *sbin = (unsigned)(t * chunk + j); *skrem = ktar - cum; }
        cum += hv;
    }
    __syncthreads();
}

// ================= cooperative single-kernel path =================
__global__ __launch_bounds__(256, 2) void ce_ohem_coop(
        const float* __restrict__ pred, const int* __restrict__ tgt,
        double* __restrict__ psum, double* __restrict__ bigp,
        unsigned* __restrict__ h1, unsigned* __restrict__ h2,
        unsigned* __restrict__ h3, double* __restrict__ s3,
        float* __restrict__ out) {
    cg::grid_group grid = cg::this_grid();
    __shared__ __align__(16) unsigned lh[4][2048];  // 32 KB, reused every phase
    __shared__ unsigned tmp[256];
    __shared__ double lred[4];
    __shared__ unsigned sbin, skrem;

    int t = threadIdx.x;
    int w = t >> 6;
    int blk = blockIdx.x;
    int gtid = blk * 256 + t;

    // zero global accumulators
    if (gtid < 2048)      h1[gtid] = 0u;
    else if (gtid < 4096) h2[gtid - 2048] = 0u;
    else if (gtid < 5120) h3[gtid - 4096] = 0u;
    else if (gtid < 6144) s3[gtid - 5120] = 0.0;
    for (int i = t; i < 4 * 2048; i += 256) ((unsigned*)lh)[i] = 0u;
    grid.sync();

    // ---- Phase A: CE (32 values/thread, kept in registers) + level-1 hist ----
    float r[32];
    double dsum = 0.0;
#pragma unroll
    for (int it = 0; it < CITERS; ++it) {
        int g  = gtid + it * (CBLOCKS * 256);
        int p0 = g << 2;
        int b  = p0 >> 19;              // / (512*1024)
        int hw = p0 & (HWSZ - 1);
        const float* base = pred + (size_t)b * (size_t)(NCLS * HWSZ) + hw;
        int4 tt = ((const int4*)tgt)[g];

        float4 s  = make_float4(0.f, 0.f, 0.f, 0.f);
        float4 vt = make_float4(0.f, 0.f, 0.f, 0.f);
#pragma unroll
        for (int c = 0; c < NCLS; ++c) {
            float4 pv = *(const float4*)(base + (size_t)c * HWSZ);
            s.x += __expf(pv.x);
            s.y += __expf(pv.y);
            s.z += __expf(pv.z);
            s.w += __expf(pv.w);
            if (c == tt.x) vt.x = pv.x;
            if (c == tt.y) vt.y = pv.y;
            if (c == tt.z) vt.z = pv.z;
            if (c == tt.w) vt.w = pv.w;
        }
        float4 rr;
        rr.x = fmaxf(__logf(s.x) - vt.x, 0.0f);
        rr.y = fmaxf(__logf(s.y) - vt.y, 0.0f);
        rr.z = fmaxf(__logf(s.z) - vt.z, 0.0f);
        rr.w = fmaxf(__logf(s.w) - vt.w, 0.0f);
        r[it * 4 + 0] = rr.x;
        r[it * 4 + 1] = rr.y;
        r[it * 4 + 2] = rr.z;
        r[it * 4 + 3] = rr.w;
        dsum += (double)rr.x + (double)rr.y + (double)rr.z + (double)rr.w;

        atomicAdd(&lh[w][__float_as_uint(rr.x) >> 21], 1u);
        atomicAdd(&lh[w][__float_as_uint(rr.y) >> 21], 1u);
        atomicAdd(&lh[w][__float_as_uint(rr.z) >> 21], 1u);
        atomicAdd(&lh[w][__float_as_uint(rr.w) >> 21], 1u);
    }
    __syncthreads();
    for (int i = t; i < 2048; i += 256) {
        unsigned c = lh[0][i] + lh[1][i] + lh[2][i] + lh[3][i];
        if (c) atomicAdd(&h1[i], c);
    }
    dsum = block_reduce_d(dsum, lred, 4);
    if (t == 0) psum[blk] = dsum;
    grid.sync();

    // ---- select1 (redundant in every block, from L2-hot h1) ----
    unsigned* h = &lh[0][0];
    for (int i = t; i < 2048; i += 256) h[i] = h1[i];
    __syncthreads();
    suffix_select(h, tmp, 8, (unsigned)KSEL, &sbin, &skrem);
    unsigned b1 = sbin, k1 = skrem;

    // ---- Phase B: level-2 hist from registers + definitely-top sum ----
    double big = 0.0;
    unsigned* l2 = &lh[1][0];
    for (int i = t; i < 2048; i += 256) l2[i] = 0u;
    __syncthreads();
#pragma unroll
    for (int i = 0; i < 32; ++i) {
        unsigned u = __float_as_uint(r[i]);
        unsigned hi = u >> 21;
        if (hi > b1) big += (double)r[i];
        else if (hi == b1) atomicAdd(&l2[(u >> 10) & 0x7FFu], 1u);
    }
    __syncthreads();
    for (int i = t; i < 2048; i += 256) {
        if (l2[i]) atomicAdd(&h2[i], l2[i]);
    }
    grid.sync();

    // ---- select2 (redundant) ----
    for (int i = t; i < 2048; i += 256) h[i] = h2[i];
    __syncthreads();
    suffix_select(h, tmp, 8, k1, &sbin, &skrem);
    unsigned b2 = sbin, k2 = skrem;

    // ---- Phase C: level-3 counts + per-bin sums from registers ----
    unsigned* l3c = &lh[2][0];            // 1024 uints
    double*   l3s = (double*)&lh[3][0];   // 1024 doubles (8 KB)
    for (int i = t; i < 1024; i += 256) { l3c[i] = 0u; l3s[i] = 0.0; }
    __syncthreads();
#pragma unroll
    for (int i = 0; i < 32; ++i) {
        unsigned u = __float_as_uint(r[i]);
        if ((u >> 21) == b1) {
            unsigned m = (u >> 10) & 0x7FFu;
            if (m > b2) big += (double)r[i];
            else if (m == b2) {
                atomicAdd(&l3c[u & 0x3FFu], 1u);
                atomicAdd(&l3s[u & 0x3FFu], (double)r[i]);
            }
        }
    }
    __syncthreads();
    for (int i = t; i < 1024; i += 256) {
        if (l3c[i]) { atomicAdd(&h3[i], l3c[i]); atomicAdd(&s3[i], l3s[i]); }
    }
    big = block_reduce_d(big, lred, 4);
    if (t == 0) bigp[blk] = big;
    grid.sync();

    // ---- Phase D: block 0 selects level 3 and finalizes ----
    if (blk == 0) {
        for (int i = t; i < 1024; i += 256) h[i] = h3[i];
        __syncthreads();
        suffix_select(h, tmp, 4, k2, &sbin, &skrem);
        unsigned b3 = sbin, krem = skrem;

        double a = 0.0;
        for (int i = t; i < CBLOCKS; i += 256) a += psum[i];
        double total = block_reduce_d(a, lred, 4);

        double bg = 0.0;
        for (int i = t; i < CBLOCKS; i += 256) bg += bigp[i];
        double bigs = block_reduce_d(bg, lred, 4);

        double sfx = 0.0;
        for (int i = t; i < 1024; i += 256) if (i > (int)b3) sfx += s3[i];
        double s3s = block_reduce_d(sfx, lred, 4);

        if (t == 0) {
            unsigned Tb = (b1 << 21) | (b2 << 10) | b3;
            double tv = (double)__uint_as_float(Tb);
            double top = bigs + s3s + (double)krem * tv;
            double loss = total / ((double)NPIX + 1e-12) + top / (double)KSEL;
            out[0] = (float)loss;
        }
    }
}

// ================= fallback multi-kernel path (round-2, proven) =================
__global__ __launch_bounds__(256) void ce_kernel(const float* __restrict__ pred,
                                                 const int* __restrict__ tgt,
                                                 float* __restrict__ ce,
                                                 double* __restrict__ psum,
                                                 unsigned* __restrict__ h1) {
    __shared__ unsigned lh[4][2048];
    __shared__ double lred[4];
    int t = threadIdx.x;
    int w = t >> 6;
    for (int i = t; i < 4 * 2048; i += 256) ((unsigned*)lh)[i] = 0u;
    __syncthreads();

    double d = 0.0;
    int tid0 = blockIdx.x * 256 + t;
#pragma unroll
    for (int it = 0; it < CE_ITERS; ++it) {
        int g  = tid0 + it * (CE_BLOCKS * 256);
        int p0 = g << 2;
        int b  = p0 >> 19;
        int hw = p0 & (HWSZ - 1);
        const float* base = pred + (size_t)b * (size_t)(NCLS * HWSZ) + hw;
        int4 tt = ((const int4*)tgt)[g];

        float4 s  = make_float4(0.f, 0.f, 0.f, 0.f);
        float4 vt = make_float4(0.f, 0.f, 0.f, 0.f);
#pragma unroll
        for (int c = 0; c < NCLS; ++c) {
            float4 pv = *(const float4*)(base + (size_t)c * HWSZ);
            s.x += __expf(pv.x);
            s.y += __expf(pv.y);
            s.z += __expf(pv.z);
            s.w += __expf(pv.w);
            if (c == tt.x) vt.x = pv.x;
            if (c == tt.y) vt.y = pv.y;
            if (c == tt.z) vt.z = pv.z;
            if (c == tt.w) vt.w = pv.w;
        }
        float4 rr;
        rr.x = fmaxf(__logf(s.x) - vt.x, 0.0f);
        rr.y = fmaxf(__logf(s.y) - vt.y, 0.0f);
        rr.z = fmaxf(__logf(s.z) - vt.z, 0.0f);
        rr.w = fmaxf(__logf(s.w) - vt.w, 0.0f);
        ((float4*)ce)[g] = rr;
        d += (double)rr.x + (double)rr.y + (double)rr.z + (double)rr.w;
        atomicAdd(&lh[w][__float_as_uint(rr.x) >> 21], 1u);
        atomicAdd(&lh[w][__float_as_uint(rr.y) >> 21], 1u);
        atomicAdd(&lh[w][__float_as_uint(rr.z) >> 21], 1u);
        atomicAdd(&lh[w][__float_as_uint(rr.w) >> 21], 1u);
    }
    __syncthreads();
    for (int i = t; i < 2048; i += 256) {
        unsigned c = lh[0][i] + lh[1][i] + lh[2][i] + lh[3][i];
        if (c) atomicAdd(&h1[i], c);
    }
    d = block_reduce_d(d, lred, 4);
    if (t == 0) psum[blockIdx.x] = d;
}

__global__ __launch_bounds__(512) void hist2_kernel(const float* __restrict__ ce,
                                                    const unsigned* __restrict__ sel,
                                                    unsigned* __restrict__ h2,
                                                    double* __restrict__ b1p) {
    __shared__ unsigned lh[2048];
    __shared__ double lred[8];
    int t = threadIdx.x;
    for (int i = t; i < 2048; i += 512) lh[i] = 0u;
    __syncthreads();
    unsigned b1 = sel[0];
    const float4* ce4 = (const float4*)ce;
    double big = 0.0;
    int tid0 = blockIdx.x * 512 + t;
#pragma unroll
    for (int it = 0; it < H_ITERS; ++it) {
        float4 x = ce4[tid0 + it * (H_BLOCKS * H_THREADS)];
        float xs[4] = {x.x, x.y, x.z, x.w};
#pragma unroll
        for (int j = 0; j < 4; ++j) {
            unsigned u = __float_as_uint(xs[j]);
            if ((u >> 21) > b1) big += (double)xs[j];
            else if ((u >> 21) == b1) atomicAdd(&lh[(u >> 10) & 0x7FFu], 1u);
        }
    }
    __syncthreads();
    for (int i = t; i < 2048; i += 512) {
        if (lh[i]) atomicAdd(&h2[i], lh[i]);
    }
    big = block_reduce_d(big, lred, 8);
    if (t == 0) b1p[blockIdx.x] = big;
}

__global__ __launch_bounds__(512) void hist3_kernel(const float* __restrict__ ce,
                                                    const unsigned* __restrict__ sel,
                                                    unsigned* __restrict__ h3,
                                                    double* __restrict__ s3,
                                                    double* __restrict__ b2p) {
    __shared__ double lred[8];
    unsigned b1 = sel[0], b2 = sel[2];
    const float4* ce4 = (const float4*)ce;
    double big = 0.0;
    int t = threadIdx.x;
    int tid0 = blockIdx.x * 512 + t;
#pragma unroll
    for (int it = 0; it < H_ITERS; ++it) {
        float4 x = ce4[tid0 + it * (H_BLOCKS * H_THREADS)];
        float xs[4] = {x.x, x.y, x.z, x.w};
#pragma unroll
        for (int j = 0; j < 4; ++j) {
            unsigned u = __float_as_uint(xs[j]);
            if ((u >> 21) == b1) {
                unsigned m = (u >> 10) & 0x7FFu;
                if (m > b2) big += (double)xs[j];
                else if (m == b2) {
                    atomicAdd(&h3[u & 0x3FFu], 1u);
                    atomicAdd(&s3[u & 0x3FFu], (double)xs[j]);
                }
            }
        }
    }
    big = block_reduce_d(big, lred, 8);
    if (t == 0) b2p[blockIdx.x] = big;
}

__global__ __launch_bounds__(256) void select_kernel(const unsigned* __restrict__ hist,
                                                     unsigned* __restrict__ sel,
                                                     int stage, int nb) {
    __shared__ unsigned h[2048];
    __shared__ unsigned tmp[256];
    __shared__ unsigned sbin, skrem;
    int t = threadIdx.x;
    for (int i = t; i < 2048; i += 256) h[i] = (i < nb) ? hist[i] : 0u;
    __syncthreads();
    unsigned ktar = (stage == 1) ? (unsigned)KSEL : sel[1];
    suffix_select(h, tmp, 8, ktar, &sbin, &skrem);
    if (t == 0) {
        if (stage == 1) { sel[0] = sbin; sel[1] = skrem; }
        else            { sel[2] = sbin; sel[3] = skrem; }
    }
}

__global__ __launch_bounds__(256) void sel3_fin_kernel(const unsigned* __restrict__ h3,
                                                       const unsigned* __restrict__ sel,
                                                       const double* __restrict__ psum,
                                                       const double* __restrict__ b1p,
                                                       const double* __restrict__ b2p,
                                                       const double* __restrict__ s3,
                                                       float* __restrict__ out) {
    __shared__ unsigned h[2048];
    __shared__ unsigned tmp[256];
    __shared__ double lred[4];
    __shared__ unsigned sbin, skrem;
    int t = threadIdx.x;
    for (int i = t; i < 2048; i += 256) h[i] = (i < 1024) ? h3[i] : 0u;
    __syncthreads();
    suffix_select(h, tmp, 8, sel[3], &sbin, &skrem);
    unsigned b3 = sbin, krem = skrem;

    double a = 0.0;
    for (int i = t; i < CE_BLOCKS; i += 256) a += psum[i];
    double total = block_reduce_d(a, lred, 4);

    double bg = b1p[t] + b1p[t + 256] + b2p[t] + b2p[t + 256];
    double bigs = block_reduce_d(bg, lred, 4);

    double sfx = 0.0;
    for (int i = t; i < 1024; i += 256) if (i > (int)b3) sfx += s3[i];
    double s3s = block_reduce_d(sfx, lred, 4);

    if (t == 0) {
        unsigned Tb = (sel[0] << 21) | (sel[2] << 10) | b3;
        double tv = (double)__uint_as_float(Tb);
        double top = bigs + s3s + (double)krem * tv;
        double loss = total / ((double)NPIX + 1e-12) + top / (double)KSEL;
        out[0] = (float)loss;
    }
}

extern "C" void kernel_launch(void* const* d_in, const int* in_sizes, int n_in,
                              void* d_out, int out_size, void* d_ws, size_t ws_size,
                              hipStream_t stream) {
    const float* pred = (const float*)d_in[0];
    const int*   tgt  = (const int*)d_in[1];
    float* out = (float*)d_out;
    char* ws = (char*)d_ws;
    double*   psum = (double*)(ws + OFF_PSUM);
    double*   bigp = (double*)(ws + OFF_BIGP);
    double*   b1p  = (double*)(ws + OFF_BIGP);
    double*   b2p  = (double*)(ws + OFF_B2P);
    unsigned* h1   = (unsigned*)(ws + OFF_H1);
    unsigned* h2   = (unsigned*)(ws + OFF_H2);
    unsigned* h3   = (unsigned*)(ws + OFF_H3);
    double*   s3   = (double*)(ws + OFF_S3);
    unsigned* sel  = (unsigned*)(ws + OFF_SEL);
    float*    ce   = (float*)(ws + OFF_CE);

    // ---- capacity pre-check (host-only queries, deterministic, capture-safe) ----
    int dev = 0;
    (void)hipGetDevice(&dev);
    int coop = 0, ncu = 0, maxb = 0;
    (void)hipDeviceGetAttribute(&coop, hipDeviceAttributeCooperativeLaunch, dev);
    (void)hipDeviceGetAttribute(&ncu, hipDeviceAttributeMultiprocessorCount, dev);
    (void)hipOccupancyMaxActiveBlocksPerMultiprocessor(&maxb, (const void*)ce_ohem_coop, 256, 0);

    if (coop && maxb > 0 && (long)maxb * (long)ncu >= (long)CBLOCKS) {
        void* args[] = { (void*)&pred, (void*)&tgt, (void*)&psum, (void*)&bigp,
                         (void*)&h1, (void*)&h2, (void*)&h3, (void*)&s3, (void*)&out };
        hipError_t e = hipLaunchCooperativeKernel((const void*)ce_ohem_coop,
                                                  dim3(CBLOCKS), dim3(256), args, 0, stream);
        if (e == hipSuccess) return;
        (void)hipGetLastError();  // clear sticky error, fall through
    }

    // ---- fallback: proven multi-kernel pipeline ----
    hipMemsetAsync(ws + OFF_H1, 0, MEMSET_LEN, stream);
    ce_kernel<<<CE_BLOCKS, 256, 0, stream>>>(pred, tgt, ce, psum, h1);
    select_kernel<<<1, 256, 0, stream>>>(h1, sel, 1, 2048);
    hist2_kernel<<<H_BLOCKS, H_THREADS, 0, stream>>>(ce, sel, h2, b1p);
    select_kernel<<<1, 256, 0, stream>>>(h2, sel, 2, 2048);
    hist3_kernel<<<H_BLOCKS, H_THREADS, 0, stream>>>(ce, sel, h3, s3, b2p);
    sel3_fin_kernel<<<1, 256, 0, stream>>>(h3, sel, psum, b1p, b2p, s3, out);
}